// Round 3
// baseline (153.750 us; speedup 1.0000x reference)
//
#include <hip/hip_runtime.h>

// Problem constants: B=32, N=128, Fin=Fout=64, K_HOPS=4
// ws layout (float offsets):
//   Tre  @ 0        : 64*64*128 = 524288   Tre[f][k][m] = T[k][m*64+f]
//   xT   @ 524288   : 32*64*128 = 262144   xT[b][f][n]  = x[b][n][f]
//   OQt  @ 786432   : 32*64*128 = 262144   OQt[b][k][n] = ((P x + Bb) Q)^T per b
//   Xft  @ 1048576  : 32*64*128 = 262144   Xft[b][f][n]
// total 1310720 floats = 5.24 MB of d_ws

#define OFF_TRE 0
#define OFF_XT  524288
#define OFF_OQT 786432
#define OFF_XFT 1048576

// k0: LDS-tiled transposes (coalesced both sides).
// blocks 0..127: Tre (k = b>>1, m-half = b&1); blocks 128..191: xT (b, n-half).
__global__ __launch_bounds__(256) void iag_k0_transpose(
    const float* __restrict__ T, const float* __restrict__ x,
    float* __restrict__ Tre, float* __restrict__ xT) {
  __shared__ float tile[64 * 65];
  int bi = blockIdx.x, tid = threadIdx.x;
  const float* src;
  float* dstbase;
  int fstride;
  if (bi < 128) {
    int k = bi >> 1, half = bi & 1;
    src = T + k * 8192 + half * 64 * 64;    // rows r=half*64.., 64 f each
    dstbase = Tre + k * 128 + half * 64;    // + f*8192 + r
    fstride = 8192;
  } else {
    int j = bi - 128;
    int b = j >> 1, half = j & 1;
    src = x + b * 8192 + half * 64 * 64;
    dstbase = xT + b * 8192 + half * 64;    // + f*128 + r
    fstride = 128;
  }
  for (int idx = tid; idx < 4096; idx += 256) {
    int c = idx & 63, r = idx >> 6;         // c = f (minor, coalesced read)
    tile[r * 65 + c] = src[idx];
  }
  __syncthreads();
  for (int idx = tid; idx < 4096; idx += 256) {
    int r = idx & 63, c = idx >> 6;         // r minor -> coalesced write
    dstbase[c * fstride + r] = tile[r * 65 + c];  // bank (r+c)%32: 2-way, free
  }
}

// k1: per (b, 32-row chunk): O = P x + Bb, then OQt[b][k][n] = (O Q)^T
__global__ __launch_bounds__(256) void iag_k1_oq(
    const float* __restrict__ x, const float* __restrict__ P,
    const float* __restrict__ Q, const float* __restrict__ Bb,
    float* __restrict__ OQt) {
  __shared__ __align__(16) float x_s[128 * 64];   // [m][k]
  __shared__ float ptile[32 * 129];               // [nl][m] = P[r0+nl][m]
  __shared__ __align__(16) float Q_s[64 * 64];    // [k][j]
  __shared__ __align__(16) float OcT[64 * 32];    // [k][nl]
  int b = blockIdx.y, r0 = blockIdx.x * 32, tid = threadIdx.x;

  const float4* xg = (const float4*)(x + b * 8192);
  float4* xs4 = (float4*)x_s;
  for (int idx = tid; idx < 2048; idx += 256) xs4[idx] = xg[idx];
  for (int idx = tid; idx < 4096; idx += 256) {
    int nl = idx >> 7, m = idx & 127;
    ptile[nl * 129 + m] = P[(r0 + nl) * 128 + m];  // coalesced read
  }
  const float4* qg = (const float4*)Q;
  float4* qs4 = (float4*)Q_s;
  for (int idx = tid; idx < 1024; idx += 256) qs4[idx] = qg[idx];
  __syncthreads();

  {  // Stage A: O[nl][k0..k0+7]
    int nl = tid & 31, k0 = (tid >> 5) * 8;
    float bias = Bb[r0 + nl];
    float a[8];
#pragma unroll
    for (int j = 0; j < 8; ++j) a[j] = bias;
#pragma unroll 4
    for (int m = 0; m < 128; ++m) {
      float p = ptile[nl * 129 + m];  // (nl+m)%32 distinct: conflict-free
      float4 x0 = xs4[m * 16 + (k0 >> 2)];
      float4 x1 = xs4[m * 16 + (k0 >> 2) + 1];
      a[0] += p * x0.x; a[1] += p * x0.y; a[2] += p * x0.z; a[3] += p * x0.w;
      a[4] += p * x1.x; a[5] += p * x1.y; a[6] += p * x1.z; a[7] += p * x1.w;
    }
#pragma unroll
    for (int j = 0; j < 8; ++j) OcT[(k0 + j) * 32 + nl] = a[j];
  }
  __syncthreads();
  {  // Stage B: OQt[b][j][r0 + nl0 .. +7]
    int j = tid >> 2, nl0 = (tid & 3) * 8;
    float c[8];
#pragma unroll
    for (int i = 0; i < 8; ++i) c[i] = 0.f;
    const float4* oc4 = (const float4*)OcT;
#pragma unroll 4
    for (int k = 0; k < 64; ++k) {
      float q = Q_s[k * 64 + j];
      float4 o0 = oc4[k * 8 + (nl0 >> 2)];
      float4 o1 = oc4[k * 8 + (nl0 >> 2) + 1];
      c[0] += q * o0.x; c[1] += q * o0.y; c[2] += q * o0.z; c[3] += q * o0.w;
      c[4] += q * o1.x; c[5] += q * o1.y; c[6] += q * o1.z; c[7] += q * o1.w;
    }
    float4* og = (float4*)(OQt + b * 8192 + j * 128 + r0 + nl0);
    og[0] = make_float4(c[0], c[1], c[2], c[3]);
    og[1] = make_float4(c[4], c[5], c[6], c[7]);
  }
}

// k2: per (f, b): G-tile in registers (16n x 4m per thread), relu,
// degree-normalize, 3 matvec hops. LDS reads: Tf lane-contiguous (conflict-
// free), OQ broadcast (2 distinct addrs/wave).
__global__ __launch_bounds__(256) void iag_k2_graph(
    const float* __restrict__ OQt_g, const float* __restrict__ Tre,
    const float* __restrict__ xT, float* __restrict__ Xft) {
  __shared__ __align__(16) float OQ_s[64 * 128];  // [k][n]
  __shared__ __align__(16) float Tf_s[64 * 128];  // [k][m]
  __shared__ float red[16 * 129];                 // 129 pad: conflict-free writes
  __shared__ float inv_c[128], inv_r[128];
  __shared__ __align__(16) float wv[128];
  __shared__ float sv[128];
  int f = blockIdx.x, b = blockIdx.y, tid = threadIdx.x;

  const float4* og = (const float4*)(OQt_g + b * 8192);
  float4* os = (float4*)OQ_s;
  for (int idx = tid; idx < 2048; idx += 256) os[idx] = og[idx];
  const float4* tg = (const float4*)(Tre + f * 8192);
  float4* ts = (float4*)Tf_s;
  for (int idx = tid; idx < 2048; idx += 256) ts[idx] = tg[idx];
  if (tid < 128) {
    float v = xT[(b * 64 + f) * 128 + tid];
    wv[tid] = v; sv[tid] = v;
  }
  __syncthreads();

  int tx = tid & 31, ty = tid >> 5;
  int m0 = tx * 4, n0 = ty * 16;

  float acc[16][4];
#pragma unroll
  for (int i = 0; i < 16; ++i)
#pragma unroll
    for (int j = 0; j < 4; ++j) acc[i][j] = 0.f;

  const float4* o4 = (const float4*)OQ_s;
  const float4* t4 = (const float4*)Tf_s;
#pragma unroll 2
  for (int k = 0; k < 64; ++k) {
    float4 bv = t4[k * 32 + tx];                  // lane-contiguous: 0 conflicts
    float bb[4] = {bv.x, bv.y, bv.z, bv.w};
    float4 a0 = o4[k * 32 + ty * 4 + 0];          // broadcast (2 addrs/wave)
    float4 a1 = o4[k * 32 + ty * 4 + 1];
    float4 a2 = o4[k * 32 + ty * 4 + 2];
    float4 a3 = o4[k * 32 + ty * 4 + 3];
    float aa[16] = {a0.x, a0.y, a0.z, a0.w, a1.x, a1.y, a1.z, a1.w,
                    a2.x, a2.y, a2.z, a2.w, a3.x, a3.y, a3.z, a3.w};
#pragma unroll
    for (int i = 0; i < 16; ++i)
#pragma unroll
      for (int j = 0; j < 4; ++j) acc[i][j] += aa[i] * bb[j];
  }
#pragma unroll
  for (int i = 0; i < 16; ++i)
#pragma unroll
    for (int j = 0; j < 4; ++j) acc[i][j] = fmaxf(acc[i][j], 0.f);

  // column sums (sum over n) -> vector indexed by m (applied at n: ref quirk)
  {
    float cs[4];
#pragma unroll
    for (int j = 0; j < 4; ++j) {
      cs[j] = 0.f;
#pragma unroll
      for (int i = 0; i < 16; ++i) cs[j] += acc[i][j];
    }
#pragma unroll
    for (int j = 0; j < 4; ++j) red[ty * 129 + m0 + j] = cs[j];
  }
  __syncthreads();
  if (tid < 128) {
    float c = 0.f;
#pragma unroll
    for (int t = 0; t < 8; ++t) c += red[t * 129 + tid];
    inv_c[tid] = 1.0f / sqrtf(c);
  }
  __syncthreads();
  // row sums (sum over m) -> vector indexed by n (applied at m: ref quirk)
  {
    float rs[16];
#pragma unroll
    for (int i = 0; i < 16; ++i) rs[i] = acc[i][0] + acc[i][1] + acc[i][2] + acc[i][3];
#pragma unroll
    for (int i = 0; i < 16; ++i) rs[i] += __shfl_xor(rs[i], 16);
    if (tx < 16) {
#pragma unroll
      for (int i = 0; i < 16; ++i) red[tx * 129 + n0 + i] = rs[i];
    }
  }
  __syncthreads();
  if (tid < 128) {
    float r = 0.f;
#pragma unroll
    for (int t = 0; t < 16; ++t) r += red[t * 129 + tid];
    inv_r[tid] = 1.0f / sqrtf(r);
  }
  __syncthreads();

  // normalize: A[n][m] = G[n][m] * inv_c[n] * inv_r[m]
  {
    float ic[16], ir[4];
#pragma unroll
    for (int i = 0; i < 16; ++i) ic[i] = inv_c[n0 + i];
#pragma unroll
    for (int j = 0; j < 4; ++j) ir[j] = inv_r[m0 + j];
#pragma unroll
    for (int i = 0; i < 16; ++i)
#pragma unroll
      for (int j = 0; j < 4; ++j) acc[i][j] *= ic[i] * ir[j];
  }

  // 3 hops: w' = A w; s += w'
  for (int h = 0; h < 3; ++h) {
    float4 w4 = ((const float4*)wv)[tx];
    float w[4] = {w4.x, w4.y, w4.z, w4.w};
    float p[16];
#pragma unroll
    for (int i = 0; i < 16; ++i)
      p[i] = acc[i][0] * w[0] + acc[i][1] * w[1] + acc[i][2] * w[2] + acc[i][3] * w[3];
#pragma unroll
    for (int i = 0; i < 16; ++i) p[i] += __shfl_xor(p[i], 16);
    if (tx < 16) {
#pragma unroll
      for (int i = 0; i < 16; ++i) red[tx * 129 + n0 + i] = p[i];
    }
    __syncthreads();
    if (tid < 128) {
      float s = 0.f;
#pragma unroll
      for (int t = 0; t < 16; ++t) s += red[t * 129 + tid];
      sv[tid] += s;
      wv[tid] = s;
    }
    __syncthreads();
  }

  if (tid < 128) Xft[(b * 64 + f) * 128 + tid] = sv[tid];
}

// k3: out[b][n][j] = sum_f Xft[b][f][n] * U[f][j]
__global__ __launch_bounds__(256) void iag_k3_out(
    const float* __restrict__ Xft, const float* __restrict__ U,
    float* __restrict__ out) {
  __shared__ __align__(16) float Xf_s[64 * 128];
  __shared__ __align__(16) float U_s[64 * 64];
  int b = blockIdx.x, tid = threadIdx.x;
  const float4* xg = (const float4*)(Xft + b * 8192);
  float4* xs = (float4*)Xf_s;
  for (int idx = tid; idx < 2048; idx += 256) xs[idx] = xg[idx];
  const float4* ug = (const float4*)U;
  float4* us = (float4*)U_s;
  for (int idx = tid; idx < 1024; idx += 256) us[idx] = ug[idx];
  __syncthreads();

  int n0 = (tid & 15) * 8, j0 = (tid >> 4) * 4;
  float acc[8][4];
#pragma unroll
  for (int i = 0; i < 8; ++i)
#pragma unroll
    for (int j = 0; j < 4; ++j) acc[i][j] = 0.f;

  const float4* x4 = (const float4*)Xf_s;
  const float4* u4 = (const float4*)U_s;
#pragma unroll 4
  for (int f = 0; f < 64; ++f) {
    float4 xa = x4[f * 32 + (n0 >> 2)];
    float4 xb = x4[f * 32 + (n0 >> 2) + 1];
    float4 u = u4[f * 16 + (j0 >> 2)];
    float xv[8] = {xa.x, xa.y, xa.z, xa.w, xb.x, xb.y, xb.z, xb.w};
    float uv[4] = {u.x, u.y, u.z, u.w};
#pragma unroll
    for (int i = 0; i < 8; ++i)
#pragma unroll
      for (int j = 0; j < 4; ++j) acc[i][j] += xv[i] * uv[j];
  }
#pragma unroll
  for (int i = 0; i < 8; ++i) {
    float4* og = (float4*)(out + b * 8192 + (n0 + i) * 64 + j0);
    og[0] = make_float4(acc[i][0], acc[i][1], acc[i][2], acc[i][3]);
  }
}

extern "C" void kernel_launch(void* const* d_in, const int* in_sizes, int n_in,
                              void* d_out, int out_size, void* d_ws, size_t ws_size,
                              hipStream_t stream) {
  const float* x  = (const float*)d_in[0];
  const float* P  = (const float*)d_in[1];
  const float* Bb = (const float*)d_in[2];
  const float* Q  = (const float*)d_in[3];
  const float* T  = (const float*)d_in[4];
  const float* U  = (const float*)d_in[5];
  float* ws = (float*)d_ws;
  float* Tre = ws + OFF_TRE;
  float* xT  = ws + OFF_XT;
  float* OQt = ws + OFF_OQT;
  float* Xft = ws + OFF_XFT;

  iag_k0_transpose<<<192, 256, 0, stream>>>(T, x, Tre, xT);
  iag_k1_oq<<<dim3(4, 32), 256, 0, stream>>>(x, P, Q, Bb, OQt);
  iag_k2_graph<<<dim3(64, 32), 256, 0, stream>>>(OQt, Tre, xT, Xft);
  iag_k3_out<<<32, 256, 0, stream>>>(Xft, U, (float*)d_out);
}

// Round 5
// 123.182 us; speedup vs baseline: 1.2482x; 1.2482x over previous
//
#include <hip/hip_runtime.h>

// B=32, N=128, Fin=Fout=64, K_HOPS=4
// ws layout (BYTE offsets), total 5 MB:
//   The  @ 0MB  : bf16-hi of Tre', [f][m][k] = 64*128*64*2 = 1 MB
//   Tle  @ 1MB  : bf16-lo,          same                   = 1 MB
//   xT   @ 2MB  : f32 [b][f][n]    32*64*128*4             = 1 MB
//   Tre  @ 3MB  : f32 [f][k][m] TEMP (k0->k0b only), 2 MB, aliased by:
//     OQh @ 3MB   : bf16-hi (OQ)^row-major [b][n][k] 32*128*64*2 = 512 KB
//     OQl @ 3.5MB : bf16-lo                                      = 512 KB
//     Xft @ 4MB   : f32 [b][f][n]                                = 1 MB
// Aliasing is safe: stream order k0 -> k0b (reads Tre) -> k1 (writes OQ*)
// -> k2 (writes Xft) -> k3.

typedef __attribute__((ext_vector_type(8))) short short8v;
typedef __attribute__((ext_vector_type(4))) float f32x4;

#define WS_THE 0u
#define WS_TLE (1u << 20)
#define WS_XT  (2u << 20)
#define WS_TRE (3u << 20)
#define WS_OQH (3u << 20)
#define WS_OQL ((3u << 20) + (512u << 10))
#define WS_XFT (4u << 20)

__device__ __forceinline__ void split_bf16(float a, unsigned& hi, unsigned& lo) {
  unsigned ha = __float_as_uint(a) & 0xffff0000u;
  float d = a - __uint_as_float(ha);          // exact (Sterbenz-adjacent)
  unsigned la = __float_as_uint(d) & 0xffff0000u;
  hi = ha; lo = la;                           // bf16 bits in TOP 16
}

// k0: LDS-tiled transposes (coalesced both sides).
// blocks 0..127: T -> Tre[f][k][m] f32 temp; blocks 128..191: x -> xT.
__global__ __launch_bounds__(256) void iag_k0_transpose(
    const float* __restrict__ T, const float* __restrict__ x,
    float* __restrict__ Tre, float* __restrict__ xT) {
  __shared__ float tile[64 * 65];
  int bi = blockIdx.x, tid = threadIdx.x;
  const float* src;
  float* dstbase;
  int fstride;
  if (bi < 128) {
    int k = bi >> 1, half = bi & 1;
    src = T + k * 8192 + half * 64 * 64;
    dstbase = Tre + k * 128 + half * 64;    // + f*8192 + r -> [f][k][m]
    fstride = 8192;
  } else {
    int j = bi - 128;
    int b = j >> 1, half = j & 1;
    src = x + b * 8192 + half * 64 * 64;
    dstbase = xT + b * 8192 + half * 64;    // + f*128 + r -> [b][f][n]
    fstride = 128;
  }
  for (int idx = tid; idx < 4096; idx += 256) {
    int c = idx & 63, r = idx >> 6;
    tile[r * 65 + c] = src[idx];
  }
  __syncthreads();
  for (int idx = tid; idx < 4096; idx += 256) {
    int r = idx & 63, c = idx >> 6;
    dstbase[c * fstride + r] = tile[r * 65 + c];
  }
}

// k0b: per f: Tre[f][k][m] f32 -> The/Tle[f][m][k] bf16 hi/lo (transpose+split)
__global__ __launch_bounds__(256) void iag_k0b_split(
    const float* __restrict__ Tre, unsigned short* __restrict__ The,
    unsigned short* __restrict__ Tle) {
  __shared__ float tile[64 * 129];
  int f = blockIdx.x, tid = threadIdx.x;
  const float* src = Tre + f * 8192;
  for (int idx = tid; idx < 8192; idx += 256) {
    int k = idx >> 7, m = idx & 127;
    tile[k * 129 + m] = src[idx];   // coalesced read
  }
  __syncthreads();
  int m = tid >> 1, kc = (tid & 1) * 32;
  unsigned hw[16], lw[16];
#pragma unroll
  for (int kk = 0; kk < 32; kk += 2) {
    float a0 = tile[(kc + kk) * 129 + m];      // bank (k+m)%32: conflict-free
    float a1 = tile[(kc + kk + 1) * 129 + m];
    unsigned h0, l0, h1, l1;
    split_bf16(a0, h0, l0);
    split_bf16(a1, h1, l1);
    hw[kk >> 1] = (h0 >> 16) | h1;
    lw[kk >> 1] = (l0 >> 16) | l1;
  }
  uint4* dh = (uint4*)(The + f * 8192 + m * 64 + kc);
  uint4* dl = (uint4*)(Tle + f * 8192 + m * 64 + kc);
#pragma unroll
  for (int i = 0; i < 4; ++i) {
    dh[i] = make_uint4(hw[4 * i], hw[4 * i + 1], hw[4 * i + 2], hw[4 * i + 3]);
    dl[i] = make_uint4(lw[4 * i], lw[4 * i + 1], lw[4 * i + 2], lw[4 * i + 3]);
  }
}

// k1: per (b, 32-row chunk): O = P x + Bb; OQh/OQl[b][n][k] = split((O Q)[n][k])
__global__ __launch_bounds__(256) void iag_k1_oq(
    const float* __restrict__ x, const float* __restrict__ P,
    const float* __restrict__ Q, const float* __restrict__ Bb,
    unsigned short* __restrict__ OQh, unsigned short* __restrict__ OQl) {
  __shared__ __align__(16) float x_s[128 * 64];   // [m][k]
  __shared__ float ptile[32 * 129];               // [nl][m]
  __shared__ __align__(16) float Q_s[64 * 64];    // [k][j]
  __shared__ __align__(16) float OcT[64 * 32];    // [k][nl]
  int b = blockIdx.y, r0 = blockIdx.x * 32, tid = threadIdx.x;

  const float4* xg = (const float4*)(x + b * 8192);
  float4* xs4 = (float4*)x_s;
  for (int idx = tid; idx < 2048; idx += 256) xs4[idx] = xg[idx];
  for (int idx = tid; idx < 4096; idx += 256) {
    int nl = idx >> 7, m = idx & 127;
    ptile[nl * 129 + m] = P[(r0 + nl) * 128 + m];
  }
  const float4* qg = (const float4*)Q;
  float4* qs4 = (float4*)Q_s;
  for (int idx = tid; idx < 1024; idx += 256) qs4[idx] = qg[idx];
  __syncthreads();

  {  // Stage A: O[nl][k0..k0+7]
    int nl = tid & 31, k0 = (tid >> 5) * 8;
    float bias = Bb[r0 + nl];
    float a[8];
#pragma unroll
    for (int j = 0; j < 8; ++j) a[j] = bias;
#pragma unroll 4
    for (int m = 0; m < 128; ++m) {
      float p = ptile[nl * 129 + m];
      float4 x0 = xs4[m * 16 + (k0 >> 2)];
      float4 x1 = xs4[m * 16 + (k0 >> 2) + 1];
      a[0] += p * x0.x; a[1] += p * x0.y; a[2] += p * x0.z; a[3] += p * x0.w;
      a[4] += p * x1.x; a[5] += p * x1.y; a[6] += p * x1.z; a[7] += p * x1.w;
    }
#pragma unroll
    for (int j = 0; j < 8; ++j) OcT[(k0 + j) * 32 + nl] = a[j];
  }
  __syncthreads();
  {  // Stage B: row n = r0 + (tid>>3), cols j0..j0+7
    int nl = tid >> 3, j0 = (tid & 7) * 8;
    float c[8];
#pragma unroll
    for (int i = 0; i < 8; ++i) c[i] = 0.f;
    const float4* q4 = (const float4*)Q_s;
#pragma unroll 4
    for (int k = 0; k < 64; ++k) {
      float o = OcT[k * 32 + nl];               // 8-lane broadcast
      float4 q0 = q4[k * 16 + (j0 >> 2)];
      float4 q1 = q4[k * 16 + (j0 >> 2) + 1];
      c[0] += o * q0.x; c[1] += o * q0.y; c[2] += o * q0.z; c[3] += o * q0.w;
      c[4] += o * q1.x; c[5] += o * q1.y; c[6] += o * q1.z; c[7] += o * q1.w;
    }
    unsigned hw[4], lw[4];
#pragma unroll
    for (int j = 0; j < 8; j += 2) {
      unsigned h0, l0, h1, l1;
      split_bf16(c[j], h0, l0);
      split_bf16(c[j + 1], h1, l1);
      hw[j >> 1] = (h0 >> 16) | h1;
      lw[j >> 1] = (l0 >> 16) | l1;
    }
    int n = r0 + nl;
    *(uint4*)(OQh + b * 8192 + n * 64 + j0) = make_uint4(hw[0], hw[1], hw[2], hw[3]);
    *(uint4*)(OQl + b * 8192 + n * 64 + j0) = make_uint4(lw[0], lw[1], lw[2], lw[3]);
  }
}

// k2: per (f, b): G = OQ^T x Tf via split-bf16 MFMA (hi*hi + hi*lo + lo*hi),
// relu, degree-normalize (ref quirk: colsum applied at n, rowsum at m),
// 3 matvec hops — all on the MFMA fragment layout.
__global__ __launch_bounds__(256) void iag_k2_graph(
    const unsigned short* __restrict__ OQh, const unsigned short* __restrict__ OQl,
    const unsigned short* __restrict__ The, const unsigned short* __restrict__ Tle,
    const float* __restrict__ xT, float* __restrict__ Xft) {
  __shared__ unsigned short Ah[128 * 72], Al[128 * 72];  // [n][k] pad->144B rows
  __shared__ unsigned short Bh[128 * 72], Bl[128 * 72];  // [m][k]
  __shared__ float red[4 * 128];
  __shared__ float invc[128], invr[128];
  __shared__ float wvb[2][128];
  int f = blockIdx.x, b = blockIdx.y, tid = threadIdx.x;

  {  // stage 4 planes, coalesced 16B chunks
    const unsigned short* sAh = OQh + b * 8192;
    const unsigned short* sAl = OQl + b * 8192;
    const unsigned short* sBh = The + f * 8192;
    const unsigned short* sBl = Tle + f * 8192;
#pragma unroll
    for (int it = 0; it < 4; ++it) {
      int c = tid + it * 256;
      int row = c >> 3, slot = c & 7;
      int so = row * 64 + slot * 8, dofs = row * 72 + slot * 8;
      *(uint4*)(Ah + dofs) = *(const uint4*)(sAh + so);
      *(uint4*)(Al + dofs) = *(const uint4*)(sAl + so);
      *(uint4*)(Bh + dofs) = *(const uint4*)(sBh + so);
      *(uint4*)(Bl + dofs) = *(const uint4*)(sBl + so);
    }
  }
  if (tid < 128) wvb[0][tid] = xT[(b * 64 + f) * 128 + tid];
  __syncthreads();

  int lane = tid & 63, w = tid >> 6;
  int li = lane & 15, lk = lane >> 4;

  // A-frags resident: wave w owns rows n in [32w, 32w+32)
  short8v ah[2][2], al[2][2];
#pragma unroll
  for (int nt = 0; nt < 2; ++nt)
#pragma unroll
    for (int kh = 0; kh < 2; ++kh) {
      int off = (w * 32 + nt * 16 + li) * 72 + kh * 32 + lk * 8;
      ah[nt][kh] = *(const short8v*)((const short*)Ah + off);
      al[nt][kh] = *(const short8v*)((const short*)Al + off);
    }

  f32x4 acc[2][8];
#pragma unroll
  for (int nt = 0; nt < 2; ++nt)
#pragma unroll
    for (int mt = 0; mt < 8; ++mt) acc[nt][mt] = (f32x4){0.f, 0.f, 0.f, 0.f};

#pragma unroll
  for (int mt = 0; mt < 8; ++mt) {
    int off = (mt * 16 + li) * 72 + lk * 8;
    short8v bh0 = *(const short8v*)((const short*)Bh + off);
    short8v bh1 = *(const short8v*)((const short*)Bh + off + 32);
    short8v bl0 = *(const short8v*)((const short*)Bl + off);
    short8v bl1 = *(const short8v*)((const short*)Bl + off + 32);
#pragma unroll
    for (int nt = 0; nt < 2; ++nt) {
      f32x4 a = acc[nt][mt];
      a = __builtin_amdgcn_mfma_f32_16x16x32_bf16(ah[nt][0], bh0, a, 0, 0, 0);
      a = __builtin_amdgcn_mfma_f32_16x16x32_bf16(ah[nt][1], bh1, a, 0, 0, 0);
      a = __builtin_amdgcn_mfma_f32_16x16x32_bf16(ah[nt][0], bl0, a, 0, 0, 0);
      a = __builtin_amdgcn_mfma_f32_16x16x32_bf16(ah[nt][1], bl1, a, 0, 0, 0);
      a = __builtin_amdgcn_mfma_f32_16x16x32_bf16(al[nt][0], bh0, a, 0, 0, 0);
      a = __builtin_amdgcn_mfma_f32_16x16x32_bf16(al[nt][1], bh1, a, 0, 0, 0);
      acc[nt][mt] = a;
    }
  }

  // relu. Lane holds D[n][m]: n = 32w + nt*16 + lk*4 + r, m = mt*16 + li.
#pragma unroll
  for (int nt = 0; nt < 2; ++nt)
#pragma unroll
    for (int mt = 0; mt < 8; ++mt)
#pragma unroll
      for (int r = 0; r < 4; ++r) acc[nt][mt][r] = fmaxf(acc[nt][mt][r], 0.f);

  // colsum c[m] = sum_n G[n][m] (inter-wave via red)
#pragma unroll
  for (int mt = 0; mt < 8; ++mt) {
    float cs = 0.f;
#pragma unroll
    for (int nt = 0; nt < 2; ++nt)
#pragma unroll
      for (int r = 0; r < 4; ++r) cs += acc[nt][mt][r];
    cs += __shfl_xor(cs, 16);
    cs += __shfl_xor(cs, 32);
    if (lk == 0) red[w * 128 + mt * 16 + li] = cs;
  }
  // rowsum r[n] = sum_m G[n][m] (intra-wave butterfly over li)
  {
    float rs[2][4];
#pragma unroll
    for (int nt = 0; nt < 2; ++nt)
#pragma unroll
      for (int r = 0; r < 4; ++r) {
        float s = 0.f;
#pragma unroll
        for (int mt = 0; mt < 8; ++mt) s += acc[nt][mt][r];
        rs[nt][r] = s;
      }
#pragma unroll
    for (int d = 1; d <= 8; d <<= 1)
#pragma unroll
      for (int nt = 0; nt < 2; ++nt)
#pragma unroll
        for (int r = 0; r < 4; ++r) rs[nt][r] += __shfl_xor(rs[nt][r], d);
    if (li == 0) {
#pragma unroll
      for (int nt = 0; nt < 2; ++nt)
#pragma unroll
        for (int r = 0; r < 4; ++r)
          invr[w * 32 + nt * 16 + lk * 4 + r] = rs[nt][r];  // raw rowsum
    }
  }
  __syncthreads();
  if (tid < 128) {
    float csum = red[tid] + red[128 + tid] + red[256 + tid] + red[384 + tid];
    invc[tid] = 1.0f / sqrtf(csum);
    invr[tid] = 1.0f / sqrtf(invr[tid]);
  }
  __syncthreads();

  // normalize: A[n][m] = G * invc[n] * invr[m]  (ref quirk preserved)
  {
    float icf[2][4], irf[8];
#pragma unroll
    for (int nt = 0; nt < 2; ++nt)
#pragma unroll
      for (int r = 0; r < 4; ++r) icf[nt][r] = invc[w * 32 + nt * 16 + lk * 4 + r];
#pragma unroll
    for (int mt = 0; mt < 8; ++mt) irf[mt] = invr[mt * 16 + li];
#pragma unroll
    for (int nt = 0; nt < 2; ++nt)
#pragma unroll
      for (int mt = 0; mt < 8; ++mt)
#pragma unroll
        for (int r = 0; r < 4; ++r) acc[nt][mt][r] *= icf[nt][r] * irf[mt];
  }

  // s = x; 3 hops: w' = A w, s += w'
  float sv[2][4];
#pragma unroll
  for (int nt = 0; nt < 2; ++nt)
#pragma unroll
    for (int r = 0; r < 4; ++r) sv[nt][r] = wvb[0][w * 32 + nt * 16 + lk * 4 + r];
  int cur = 0;
  for (int h = 0; h < 3; ++h) {
    float wr[8];
#pragma unroll
    for (int mt = 0; mt < 8; ++mt) wr[mt] = wvb[cur][mt * 16 + li];
    float p[2][4];
#pragma unroll
    for (int nt = 0; nt < 2; ++nt)
#pragma unroll
      for (int r = 0; r < 4; ++r) {
        float s = 0.f;
#pragma unroll
        for (int mt = 0; mt < 8; ++mt) s += acc[nt][mt][r] * wr[mt];
        p[nt][r] = s;
      }
#pragma unroll
    for (int d = 1; d <= 8; d <<= 1)
#pragma unroll
      for (int nt = 0; nt < 2; ++nt)
#pragma unroll
        for (int r = 0; r < 4; ++r) p[nt][r] += __shfl_xor(p[nt][r], d);
#pragma unroll
    for (int nt = 0; nt < 2; ++nt)
#pragma unroll
      for (int r = 0; r < 4; ++r) sv[nt][r] += p[nt][r];
    if (li == 0) {
#pragma unroll
      for (int nt = 0; nt < 2; ++nt)
#pragma unroll
        for (int r = 0; r < 4; ++r)
          wvb[cur ^ 1][w * 32 + nt * 16 + lk * 4 + r] = p[nt][r];
    }
    __syncthreads();
    cur ^= 1;
  }
  if (li == 0) {
#pragma unroll
    for (int nt = 0; nt < 2; ++nt)
#pragma unroll
      for (int r = 0; r < 4; ++r)
        Xft[(b * 64 + f) * 128 + w * 32 + nt * 16 + lk * 4 + r] = sv[nt][r];
  }
}

// k3: out[b][n][j] = sum_f Xft[b][f][n] * U[f][j]; grid (4 n-chunks, 32 b)
__global__ __launch_bounds__(256) void iag_k3_out(
    const float* __restrict__ Xft, const float* __restrict__ U,
    float* __restrict__ out) {
  __shared__ float Xf_s[64 * 36];                 // [f][nl], 144B rows
  __shared__ __align__(16) float U_s[64 * 64];
  int b = blockIdx.y, n0 = blockIdx.x * 32, tid = threadIdx.x;
  for (int c = tid; c < 512; c += 256) {
    int ff = c >> 3, s = c & 7;
    float4 v = *(const float4*)(Xft + (b * 64 + ff) * 128 + n0 + s * 4);
    *(float4*)(Xf_s + ff * 36 + s * 4) = v;
  }
  const float4* ug = (const float4*)U;
  float4* us = (float4*)U_s;
  for (int c = tid; c < 1024; c += 256) us[c] = ug[c];
  __syncthreads();

  int j0 = (tid & 15) * 4, nl0 = (tid >> 4) * 2;
  float a0[4] = {0.f, 0.f, 0.f, 0.f}, a1[4] = {0.f, 0.f, 0.f, 0.f};
  const float4* u4 = (const float4*)U_s;
#pragma unroll 4
  for (int ff = 0; ff < 64; ++ff) {
    float4 u = u4[ff * 16 + (j0 >> 2)];
    float xa = Xf_s[ff * 36 + nl0];
    float xb = Xf_s[ff * 36 + nl0 + 1];
    a0[0] += xa * u.x; a0[1] += xa * u.y; a0[2] += xa * u.z; a0[3] += xa * u.w;
    a1[0] += xb * u.x; a1[1] += xb * u.y; a1[2] += xb * u.z; a1[3] += xb * u.w;
  }
  *(float4*)(out + b * 8192 + (n0 + nl0) * 64 + j0) =
      make_float4(a0[0], a0[1], a0[2], a0[3]);
  *(float4*)(out + b * 8192 + (n0 + nl0 + 1) * 64 + j0) =
      make_float4(a1[0], a1[1], a1[2], a1[3]);
}

extern "C" void kernel_launch(void* const* d_in, const int* in_sizes, int n_in,
                              void* d_out, int out_size, void* d_ws, size_t ws_size,
                              hipStream_t stream) {
  const float* x  = (const float*)d_in[0];
  const float* P  = (const float*)d_in[1];
  const float* Bb = (const float*)d_in[2];
  const float* Q  = (const float*)d_in[3];
  const float* T  = (const float*)d_in[4];
  const float* U  = (const float*)d_in[5];
  char* wsb = (char*)d_ws;
  unsigned short* The = (unsigned short*)(wsb + WS_THE);
  unsigned short* Tle = (unsigned short*)(wsb + WS_TLE);
  float* xT  = (float*)(wsb + WS_XT);
  float* Tre = (float*)(wsb + WS_TRE);
  unsigned short* OQh = (unsigned short*)(wsb + WS_OQH);
  unsigned short* OQl = (unsigned short*)(wsb + WS_OQL);
  float* Xft = (float*)(wsb + WS_XFT);

  iag_k0_transpose<<<192, 256, 0, stream>>>(T, x, Tre, xT);
  iag_k0b_split<<<64, 256, 0, stream>>>(Tre, The, Tle);
  iag_k1_oq<<<dim3(4, 32), 256, 0, stream>>>(x, P, Q, Bb, OQh, OQl);
  iag_k2_graph<<<dim3(64, 32), 256, 0, stream>>>(OQh, OQl, The, Tle, xT, Xft);
  iag_k3_out<<<dim3(4, 32), 256, 0, stream>>>(Xft, U, (float*)d_out);
}